// Round 17
// baseline (54.920 us; speedup 1.0000x reference)
//
#include <hip/hip_runtime.h>
#include <math.h>

// TopDownHTMM: C=32, 4-ary tree depth 7, N=21845, M=256. Output: scalar fp32.
// THREE kernels = r14's verified 4-kernel structure with k_final folded into
// k_eps via int-ticket last-block reduce (no float atomics, no polling):
//   k_sub2 (256x1024): tables in-block (block 0 exports sAT/sA/sLT, B-stats,
//                      Pi; blocks 0..84 export top label rows), path prior,
//                      down 5-7, up 7-5; exports TB4 + t_beta/ratio stash;
//                      zeroes the ticket.
//   k_mid  (1x1024):   pure-import; top-down 0-3, top-up from TB4, full
//                      top-eps + top lh; exports EPSM + W_PART[256].
//   k_eps  (256x1024): import tables/stats; stash->LDS; subtree eps 4-7 + lh
//                      -> W_PART[bid]; ticket; last block sums 257 partials
//                      in fixed order -> out[0].
//
// Subtree r in [85,341): local m in [0,85), depth d, global g = 4^d*r + m;
// parent=(m-1)>>2, pos=(m-1)&3 hold locally. Class invariant: for level
// starts {1,5,21,85} and base stepping by 32, e=(m-1)&3 == grp&3.

#define NF (21845 * 32)

enum : int {
  W_TBETA = 0,              // [N][32] rows 85..21844
  W_RATIO = NF,             // [N][32] (beta_final/prior)
  W_TB4   = 2 * NF,         // [256][32] level-4 t_beta (index r-85)
  W_EPSM  = 2 * NF + 8192,  // [85][32] top eps rows
  W_PART  = W_EPSM + 2720,  // 257 lh partials; [258] = int ticket
  W_TABA  = W_PART + 260,   // sAT  [e][j][i] sm            (4096)
  W_TABU  = W_TABA + 4096,  // sA   [e][i][j] sm            (4096)
  W_TABL  = W_TABU + 4096,  // sLT  [e][j][i] sm*log        (4096)
  W_BST   = W_TABL + 4096,  // bmx[32], binv[32], bls[32]   (96)
  W_PIV   = W_BST + 96,     // sPi[32], lPi[32]             (64)
  W_TOPS  = W_PIV + 64,     // top smB label rows [85][32]  (2720)
  W_TOPL  = W_TOPS + 2720,  // top logB label rows [85][32] (2720)
};

__device__ inline float hsum32(float v) {
#pragma unroll
  for (int m = 16; m >= 1; m >>= 1) v += __shfl_xor(v, m, 32);
  return v;
}
__device__ inline float hmax32(float v) {
#pragma unroll
  for (int m = 16; m >= 1; m >>= 1) v = fmaxf(v, __shfl_xor(v, m, 32));
  return v;
}
__device__ inline int gmap(int r, int m) {
  return (m == 0) ? r : (m < 5 ? 4 * r + m : (m < 21 ? 16 * r + m : 64 * r + m));
}

// reg-table matvec: out[lane] = sum_j T[j] * vec[j]; vec via b128 broadcast.
__device__ inline float mvreg(const float (&T)[32], const float* __restrict__ vec) {
  const float4* v4 = (const float4*)vec;
  float a0 = 0.f, a1 = 0.f, a2 = 0.f, a3 = 0.f;
#pragma unroll
  for (int j4 = 0; j4 < 8; j4++) {
    float4 v = v4[j4];
    a0 += T[4 * j4 + 0] * v.x; a1 += T[4 * j4 + 1] * v.y;
    a2 += T[4 * j4 + 2] * v.z; a3 += T[4 * j4 + 3] * v.w;
  }
  return (a0 + a1) + (a2 + a3);
}
__device__ inline void mvreg2(const float (&Tn)[32], const float (&Tl)[32],
                              const float* __restrict__ vec, float& an, float& aa) {
  const float4* v4 = (const float4*)vec;
  float n0 = 0.f, n1 = 0.f, n2 = 0.f, n3 = 0.f;
  float l0 = 0.f, l1 = 0.f, l2 = 0.f, l3 = 0.f;
#pragma unroll
  for (int j4 = 0; j4 < 8; j4++) {
    float4 v = v4[j4];
    n0 += Tn[4 * j4 + 0] * v.x; n1 += Tn[4 * j4 + 1] * v.y;
    n2 += Tn[4 * j4 + 2] * v.z; n3 += Tn[4 * j4 + 3] * v.w;
    l0 += Tl[4 * j4 + 0] * v.x; l1 += Tl[4 * j4 + 1] * v.y;
    l2 += Tl[4 * j4 + 2] * v.z; l3 += Tl[4 * j4 + 3] * v.w;
  }
  an = (n0 + n1) + (n2 + n3);
  aa = (l0 + l1) + (l2 + l3);
}

// ---------------- K1: per-subtree down 5-7 + up 7-5 + exports ---------------
__global__ __launch_bounds__(1024, 4) void k_sub2(const float* __restrict__ A,
                                                  const float* __restrict__ Bm,
                                                  const float* __restrict__ Pi,
                                                  const int* __restrict__ labels,
                                                  float* __restrict__ W) {
  __shared__ __align__(16) float sAT[4096], sA[4096];
  __shared__ __align__(16) float SH[10880];
  __shared__ float smx[128], sinv[128], sls[128];
  __shared__ float sBmx[32], sBinv[32], sBls[32];
  __shared__ __align__(16) float spath[32];
  __shared__ float sp3v[32];
  float* sp  = SH;          float* sb  = SH + 2720;
  float* stb = SH + 5440;   float* slb = SH + 8160;
  float* S   = SH;          // staging 4224 floats, dead after build

  const int tid = threadIdx.x, bid = blockIdx.x;
  const int grp = tid >> 5, lane = tid & 31;
  const int ecl = grp & 3, slot = grp >> 2;
  const int r = 85 + bid;
  if (bid == 0 && tid == 0) ((int*)(W + W_PART))[258] = 0;  // zero ticket

  {  // B row stats (+ export by block 0)
    float xs[8], mx = -1e30f;
#pragma unroll
    for (int k = 0; k < 8; k++) { xs[k] = Bm[grp * 256 + k * 32 + lane]; mx = fmaxf(mx, xs[k]); }
    mx = hmax32(mx);
    float s = 0.f;
#pragma unroll
    for (int k = 0; k < 8; k++) s += expf(xs[k] - mx);
    s = hsum32(s);
    if (lane == 0) {
      float ls = logf(s);
      sBmx[grp] = mx; sBinv[grp] = 1.f / s; sBls[grp] = ls;
      if (bid == 0) { W[W_BST + grp] = mx; W[W_BST + 32 + grp] = 1.f / s; W[W_BST + 64 + grp] = ls; }
    }
  }
  {  // stage raw A -> padded S
    float4 raw = ((const float4*)A)[tid];
    int i = tid >> 5, j = tid & 31;
    S[(j * 4 + 0) * 33 + i] = raw.x;
    S[(j * 4 + 1) * 33 + i] = raw.y;
    S[(j * 4 + 2) * 33 + i] = raw.z;
    S[(j * 4 + 3) * 33 + i] = raw.w;
  }
  __syncthreads();
  if (tid < 128) {  // column stats (c = j*4+e) — serial form (r14-verified)
    int c = tid;
    float mx = -1e30f;
    for (int i = 0; i < 32; i++) mx = fmaxf(mx, S[c * 33 + i]);
    float s = 0.f;
    for (int i = 0; i < 32; i++) s += expf(S[c * 33 + i] - mx);
    smx[c] = mx; sinv[c] = 1.f / s; sls[c] = logf(s);
  }
  __syncthreads();
  {  // emit sAT [e][j][i]; block 0 also exports sAT + sLT (sm*log)
    int v = 4 * tid, e = v >> 10, j = (v >> 5) & 31, i0 = v & 31, c = j * 4 + e;
    float mx = smx[c], iv = sinv[c], ls = sls[c];
    float x0 = S[c * 33 + i0 + 0], x1 = S[c * 33 + i0 + 1];
    float x2 = S[c * 33 + i0 + 2], x3 = S[c * 33 + i0 + 3];
    float s0 = expf(x0 - mx) * iv, s1 = expf(x1 - mx) * iv;
    float s2 = expf(x2 - mx) * iv, s3 = expf(x3 - mx) * iv;
    float4 o; o.x = s0; o.y = s1; o.z = s2; o.w = s3;
    ((float4*)sAT)[tid] = o;
    if (bid == 0) {
      ((float4*)(W + W_TABA))[tid] = o;
      float4 ol;
      ol.x = s0 * ((x0 - mx) - ls); ol.y = s1 * ((x1 - mx) - ls);
      ol.z = s2 * ((x2 - mx) - ls); ol.w = s3 * ((x3 - mx) - ls);
      ((float4*)(W + W_TABL))[tid] = ol;
    }
  }
  {  // emit sA [e][i][j]; block 0 exports
    int v = 4 * tid, e = v >> 10, i = (v >> 5) & 31, j0 = v & 31;
    float4 o;
    { int c = (j0 + 0) * 4 + e; o.x = expf(S[c * 33 + i] - smx[c]) * sinv[c]; }
    { int c = (j0 + 1) * 4 + e; o.y = expf(S[c * 33 + i] - smx[c]) * sinv[c]; }
    { int c = (j0 + 2) * 4 + e; o.z = expf(S[c * 33 + i] - smx[c]) * sinv[c]; }
    { int c = (j0 + 3) * 4 + e; o.w = expf(S[c * 33 + i] - smx[c]) * sinv[c]; }
    ((float4*)sA)[tid] = o;
    if (bid == 0) ((float4*)(W + W_TABU))[tid] = o;
  }
  __syncthreads();  // S dead

  {  // smB label rows (static 3-slot)
    const int m0 = grp, m1 = grp + 32, m2 = grp + 64;
    float bmx = sBmx[lane], binv = sBinv[lane];
    float x0 = Bm[lane * 256 + labels[gmap(r, m0)]];
    float x1 = Bm[lane * 256 + labels[gmap(r, m1)]];
    slb[m0 * 32 + lane] = expf(x0 - bmx) * binv;
    slb[m1 * 32 + lane] = expf(x1 - bmx) * binv;
    if (m2 < 85) {
      float x2 = Bm[lane * 256 + labels[gmap(r, m2)]];
      slb[m2 * 32 + lane] = expf(x2 - bmx) * binv;
    }
  }
  // top label row export: block b (<85) exports top node b's row (sm + log)
  if (bid < 85 && tid < 32) {
    float x = Bm[tid * 256 + labels[bid]];
    W[W_TOPS + bid * 32 + tid] = expf(x - sBmx[tid]) * sBinv[tid];
    W[W_TOPL + bid * 32 + tid] = (x - sBmx[tid]) - sBls[tid];
  }
  {  // smPi -> spath (+ export by block 0)
    float x = Pi[lane];
    float mx = hmax32(x);
    float ex = expf(x - mx);
    float s = hsum32(ex);
    float pPi = ex / s;
    if (tid < 32) {
      spath[tid] = pPi;
      if (bid == 0) { W[W_PIV + tid] = pPi; W[W_PIV + 32 + tid] = (x - mx) - logf(s); }
    }
  }
  float D[32];
#pragma unroll
  for (int j = 0; j < 32; j++) D[j] = sAT[(grp & 3) * 1024 + j * 32 + lane];
  __syncthreads();

  const int a3n = (r - 1) >> 2, a2n = (a3n - 1) >> 2, a1n = (a2n - 1) >> 2;
  const int pe0 = (a1n - 1) & 3, pe1 = (a2n - 1) & 3, pe2 = (a3n - 1) & 3, pe3 = (r - 1) & 3;
  if (ecl == pe0 && slot == 0) spath[lane] = mvreg(D, spath);
  __syncthreads();
  if (ecl == pe1 && slot == 0) spath[lane] = mvreg(D, spath);
  __syncthreads();
  if (ecl == pe2 && slot == 0) { float a = mvreg(D, spath); spath[lane] = a; sp3v[lane] = a; }
  __syncthreads();
  if (ecl == pe3 && slot == 0) spath[lane] = mvreg(D, spath);
  __syncthreads();
  if (tid < 32) { sp[tid] = spath[tid]; sb[tid] = spath[tid] * slb[tid]; }
  __syncthreads();

  const int LOFF[5] = {0, 1, 5, 21, 85};
  for (int d = 1; d <= 3; d++) {
    int st = LOFF[d], cnt = LOFF[d + 1] - st;
    for (int base = 0; base < cnt; base += 32) {
      int ix = base + grp;
      if (ix < cnt) {
        int m = st + ix, pam = (m - 1) >> 2;
        float acc = mvreg(D, &sp[pam * 32]);
        sp[m * 32 + lane] = acc;
        float bv = acc * slb[m * 32 + lane];
        if (d == 3) bv /= hsum32(bv);
        sb[m * 32 + lane] = bv;
      }
    }
    __syncthreads();
  }
  float U[32];
#pragma unroll
  for (int i = 0; i < 32; i++) U[i] = sA[(grp & 3) * 1024 + i * 32 + lane];
  for (int d = 2; d >= 0; d--) {
    int pst = LOFF[d], pcnt = LOFF[d + 1] - pst;
    for (int base = 0; base < pcnt; base += 8) {
      int pidx = base + slot;
      if (pidx < pcnt) {
        int pn = pst + pidx;
        int mch = 4 * pn + 1 + ecl;
        stb[mch * 32 + lane] = mvreg(U, &sb[mch * 32]) / sp[pn * 32 + lane];
      }
    }
    __syncthreads();
    if (grp < pcnt) {
      int pn = pst + grp;
      float prod = stb[(4 * pn + 1) * 32 + lane] * stb[(4 * pn + 2) * 32 + lane]
                 * stb[(4 * pn + 3) * 32 + lane] * stb[(4 * pn + 4) * 32 + lane];
      float bn = sb[pn * 32 + lane] * prod;
      bn /= hsum32(bn);
      sb[pn * 32 + lane] = bn;
    }
    __syncthreads();
  }
  if (ecl == pe3 && slot == 0) {
    float acc = mvreg(U, &sb[0]);
    float tb = acc / sp3v[lane];
    stb[lane] = tb;
    W[W_TB4 + bid * 32 + lane] = tb;
  }
  __syncthreads();
  if (tid < 680) {
    int m = tid >> 3, q = tid & 7, g = gmap(r, m);
    *(float4*)&W[W_TBETA + g * 32 + q * 4] = *(float4*)&stb[m * 32 + q * 4];
    float4 bb = *(float4*)&sb[m * 32 + q * 4], pp = *(float4*)&sp[m * 32 + q * 4];
    float4 rr;
    rr.x = bb.x / pp.x; rr.y = bb.y / pp.y; rr.z = bb.z / pp.z; rr.w = bb.w / pp.w;
    *(float4*)&W[W_RATIO + g * 32 + q * 4] = rr;
  }
}

// ---------------- K2: top tree + full top-eps + top lh (pure import) --------
__global__ __launch_bounds__(1024, 4) void k_mid(float* __restrict__ W) {
  __shared__ __align__(16) float sAT[4096], sA[4096], sLT[4096];
  __shared__ __align__(16) float R[8192];    // TB4
  __shared__ __align__(16) float U[16320];
  __shared__ __align__(16) float sq[1024];
  __shared__ float sred[16];
  float* msp   = U;            float* msb   = U + 2720;
  float* mstb  = U + 5440;     float* mslbS = U + 8160;
  float* mseps = U + 10880;    float* mslbL = U + 13600;

  const int tid = threadIdx.x;
  const int grp = tid >> 5, lane = tid & 31;
  const int LOFF[5] = {0, 1, 5, 21, 85};

  // ---- issue ALL imports up front ----
  float4 tA = ((const float4*)(W + W_TABA))[tid];
  float4 tU = ((const float4*)(W + W_TABU))[tid];
  float4 tL = ((const float4*)(W + W_TABL))[tid];
  float4 r0 = ((const float4*)(W + W_TB4))[tid];
  float4 r1 = ((const float4*)(W + W_TB4))[tid + 1024];
  float4 tS, tLg;
  if (tid < 680) {
    tS  = ((const float4*)(W + W_TOPS))[tid];
    tLg = ((const float4*)(W + W_TOPL))[tid];
  }
  float pv = 0.f, lv = 0.f;
  if (tid < 32) { pv = W[W_PIV + tid]; lv = W[W_PIV + 32 + tid]; }

  ((float4*)sAT)[tid] = tA;
  ((float4*)sA)[tid]  = tU;
  ((float4*)sLT)[tid] = tL;
  ((float4*)R)[tid] = r0; ((float4*)R)[tid + 1024] = r1;
  if (tid < 680) { ((float4*)mslbS)[tid] = tS; ((float4*)mslbL)[tid] = tLg; }
  if (tid < 32) msp[tid] = pv;
  __syncthreads();

  float D[32], L[32];
#pragma unroll
  for (int j = 0; j < 32; j++) D[j] = sAT[(grp & 3) * 1024 + j * 32 + lane];
#pragma unroll
  for (int j = 0; j < 32; j++) L[j] = sLT[(grp & 3) * 1024 + j * 32 + lane];
  if (grp == 0) msb[lane] = msp[lane] * mslbS[lane];
  __syncthreads();

  // top-down levels 1..3
  for (int l = 1; l <= 3; l++) {
    int st = LOFF[l], cnt = LOFF[l + 1] - st;
    for (int base = 0; base < cnt; base += 32) {
      int ix = base + grp;
      if (ix < cnt) {
        int n = st + ix, pa = (n - 1) >> 2;
        float acc = mvreg(D, &msp[pa * 32]);
        msp[n * 32 + lane] = acc;
        msb[n * 32 + lane] = acc * mslbS[n * 32 + lane];
      }
    }
    __syncthreads();
  }
  // top-up: level-3 parents from TB4, then 2,1,0
  {
    for (int base = 0; base < 64; base += 32) {
      int ix = base + grp;
      if (ix < 64) {
        int pn = 21 + ix;
        float prod = 1.f;
#pragma unroll
        for (int c = 0; c < 4; c++) prod *= R[(4 * pn + 1 + c - 85) * 32 + lane];
        float bn = msb[pn * 32 + lane] * prod;
        bn /= hsum32(bn);
        msb[pn * 32 + lane] = bn;
      }
    }
    __syncthreads();
    const int PST[3] = {5, 1, 0}, PCNT[3] = {16, 4, 1};
    for (int s = 0; s < 3; s++) {
      int st = PST[s], cnt = PCNT[s];
      if (grp < cnt) {
        int pn = st + grp;
        float ppj = msp[pn * 32 + lane];
        float ac[4] = {0.f, 0.f, 0.f, 0.f};
#pragma unroll
        for (int j4 = 0; j4 < 8; j4++) {
#pragma unroll
          for (int c = 0; c < 4; c++) {
            float4 v = ((const float4*)&msb[(4 * pn + 1 + c) * 32])[j4];
            const float* t = &sA[c * 1024 + j4 * 128 + lane];
            ac[c] += t[0] * v.x + t[32] * v.y + t[64] * v.z + t[96] * v.w;
          }
        }
        float prod = 1.f;
#pragma unroll
        for (int c = 0; c < 4; c++) {
          float buv = ac[c] / ppj;
          mstb[(4 * pn + 1 + c) * 32 + lane] = buv;
          prod *= buv;
        }
        float bn = msb[pn * 32 + lane] * prod;
        bn /= hsum32(bn);
        msb[pn * 32 + lane] = bn;
      }
      __syncthreads();
    }
  }

  float lh = 0.f;
  if (grp == 0) {
    float v = msb[lane];
    mseps[lane] = v;
    lh += v * (lv + mslbL[lane]);  // Pi_lh + root B_lh
  }
  __syncthreads();
  const int EST[3] = {1, 5, 21}, ECNT[3] = {4, 16, 64};
  for (int s = 0; s < 3; s++) {
    int st = EST[s], cnt = ECNT[s];
    for (int base = 0; base < cnt; base += 32) {
      int ix = base + grp;
      if (ix < cnt) {
        int n = st + ix, pa = (n - 1) >> 2;
        float ratio = msb[n * 32 + lane] / msp[n * 32 + lane];
        float qv = mseps[pa * 32 + lane] / mstb[n * 32 + lane];
        sq[grp * 32 + lane] = qv;
        float an, aa;
        mvreg2(D, L, &sq[grp * 32], an, aa);
        float num = ratio * an;
        float den = hsum32(num);
        float epsi = num / den;
        mseps[n * 32 + lane] = epsi;
        lh += ratio * aa + epsi * mslbL[n * 32 + lane];
      }
    }
    __syncthreads();
  }
  if (tid < 680) {  // export eps rows 0..84
    int m = tid >> 3, q = tid & 7;
    *(float4*)&W[W_EPSM + m * 32 + q * 4] = *(float4*)&mseps[m * 32 + q * 4];
  }
#pragma unroll
  for (int mm = 32; mm >= 1; mm >>= 1) lh += __shfl_xor(lh, mm, 64);
  if ((tid & 63) == 0) sred[tid >> 6] = lh;
  __syncthreads();
  if (tid == 0) {
    float t = 0.f;
#pragma unroll
    for (int w = 0; w < 16; w++) t += sred[w];
    W[W_PART + 256] = t;
  }
}

// ---------------- K3: per-subtree eps 4-7 + lh + last-block final -----------
__global__ __launch_bounds__(1024, 4) void k_eps(const float* __restrict__ Bm,
                                                 const int* __restrict__ labels,
                                                 float* __restrict__ W,
                                                 float* __restrict__ out) {
  __shared__ __align__(16) float sAT[4096], sLT[4096];
  __shared__ __align__(16) float V[10880];
  __shared__ __align__(16) float sq[1024];
  __shared__ __align__(16) float sqr[32];
  __shared__ float spe[32];
  __shared__ float sbst[96];
  __shared__ float sred[16];
  __shared__ int sLast;
  float* stb  = V;            float* srt  = V + 2720;
  float* seps = V + 5440;     float* slbL = V + 8160;

  const int tid = threadIdx.x, bid = blockIdx.x;
  const int grp = tid >> 5, lane = tid & 31;
  const int ecl = grp & 3, slot = grp >> 2;
  const int r = 85 + bid;
  const int LOFF[5] = {0, 1, 5, 21, 85};

  // ---- issue ALL global loads up front ----
  float4 stT, stR;
  const int sm_ = tid >> 3, sq_ = tid & 7;
  if (tid < 680) {
    int g = gmap(r, sm_);
    stT = *(const float4*)&W[W_TBETA + g * 32 + sq_ * 4];
    stR = *(const float4*)&W[W_RATIO + g * 32 + sq_ * 4];
  }
  float4 tA = ((const float4*)(W + W_TABA))[tid];
  float4 tL = ((const float4*)(W + W_TABL))[tid];
  float pe = 0.f;
  if (tid < 32) pe = W[W_EPSM + ((r - 1) >> 2) * 32 + tid];
  float bv = 0.f;
  if (tid < 96) bv = W[W_BST + tid];
  const int m0 = grp, m1 = grp + 32, m2 = grp + 64;
  const bool h2 = (m2 < 85);
  int lb0 = labels[gmap(r, m0)];
  int lb1 = labels[gmap(r, m1)];
  int lb2 = h2 ? labels[gmap(r, m2)] : 0;
  float xs0 = Bm[lane * 256 + lb0];
  float xs1 = Bm[lane * 256 + lb1];
  float xs2 = h2 ? Bm[lane * 256 + lb2] : 0.f;

  ((float4*)sAT)[tid] = tA;
  ((float4*)sLT)[tid] = tL;
  if (tid < 32) spe[tid] = pe;
  if (tid < 96) sbst[tid] = bv;
  if (tid < 680) {
    *(float4*)&stb[sm_ * 32 + sq_ * 4] = stT;
    *(float4*)&srt[sm_ * 32 + sq_ * 4] = stR;
  }
  __syncthreads();

  {  // log-B label rows (bmx = sbst[lane], bls = sbst[64+lane])
    float bmx = sbst[lane], bls = sbst[64 + lane];
    slbL[m0 * 32 + lane] = (xs0 - bmx) - bls;
    slbL[m1 * 32 + lane] = (xs1 - bmx) - bls;
    if (h2) slbL[m2 * 32 + lane] = (xs2 - bmx) - bls;
  }
  float D[32], L[32];
#pragma unroll
  for (int j = 0; j < 32; j++) D[j] = sAT[(grp & 3) * 1024 + j * 32 + lane];
#pragma unroll
  for (int j = 0; j < 32; j++) L[j] = sLT[(grp & 3) * 1024 + j * 32 + lane];
  __syncthreads();

  float lh = 0.f;
  // eps at level-4 root r (class-matching group)
  if (ecl == ((r - 1) & 3) && slot == 0) {
    float ratio = srt[lane];
    sqr[lane] = spe[lane] / stb[lane];
    float an, aa;
    mvreg2(D, L, sqr, an, aa);
    float num = ratio * an;
    float den = hsum32(num);
    float epsi = num / den;
    seps[lane] = epsi;
    lh += ratio * aa + epsi * slbL[lane];
  }
  __syncthreads();
  // subtree eps levels 1..3 (global 5..7); e == grp&3
  for (int d = 1; d <= 3; d++) {
    int st = LOFF[d], cnt = LOFF[d + 1] - st;
    for (int base = 0; base < cnt; base += 32) {
      int ix = base + grp;
      if (ix < cnt) {
        int m = st + ix, pa = (m - 1) >> 2;
        float ratio = srt[m * 32 + lane];
        sq[grp * 32 + lane] = seps[pa * 32 + lane] / stb[m * 32 + lane];
        float an, aa;
        mvreg2(D, L, &sq[grp * 32], an, aa);
        float num = ratio * an;
        float den = hsum32(num);
        float epsi = num / den;
        seps[m * 32 + lane] = epsi;
        lh += ratio * aa + epsi * slbL[m * 32 + lane];
      }
    }
    __syncthreads();
  }

  // ---- block partial -> PART[bid]; ticket; last block does final reduce ----
#pragma unroll
  for (int mm = 32; mm >= 1; mm >>= 1) lh += __shfl_xor(lh, mm, 64);
  if ((tid & 63) == 0) sred[tid >> 6] = lh;
  __syncthreads();
  if (tid == 0) {
    float t = 0.f;
#pragma unroll
    for (int w = 0; w < 16; w++) t += sred[w];
    W[W_PART + bid] = t;
    __threadfence();  // release PART[bid] before ticket
    int prev = __hip_atomic_fetch_add(&((int*)(W + W_PART))[258], 1,
                                      __ATOMIC_ACQ_REL, __HIP_MEMORY_SCOPE_AGENT);
    sLast = (prev == 255) ? 1 : 0;
  }
  __syncthreads();
  if (sLast) {
    __threadfence();  // acquire: see all PART writes
    if (tid < 64) {
      float a = 0.f;
      for (int k = tid; k < 257; k += 64) a += W[W_PART + k];
#pragma unroll
      for (int mm = 32; mm >= 1; mm >>= 1) a += __shfl_xor(a, mm, 64);
      if (tid == 0) out[0] = a;
    }
  }
}

extern "C" void kernel_launch(void* const* d_in, const int* in_sizes, int n_in,
                              void* d_out, int out_size, void* d_ws, size_t ws_size,
                              hipStream_t stream) {
  const float* A  = (const float*)d_in[0];
  const float* Bm = (const float*)d_in[1];
  const float* Pi = (const float*)d_in[2];
  const int* labels = (const int*)d_in[5];
  float* W = (float*)d_ws;
  float* out = (float*)d_out;

  k_sub2<<<256, 1024, 0, stream>>>(A, Bm, Pi, labels, W);
  k_mid<<<1, 1024, 0, stream>>>(W);
  k_eps<<<256, 1024, 0, stream>>>(Bm, labels, W, out);
}

// Round 18
// 43.869 us; speedup vs baseline: 1.2519x; 1.2519x over previous
//
#include <hip/hip_runtime.h>
#include <math.h>

// TopDownHTMM: C=32, 4-ary tree depth 7, N=21845, M=256. Output: scalar fp32.
// FOUR kernels — VERIFIED BEST (round 14, 43.9us). No device-scope sync of any
// kind inside kernels: r6 (flag poll) = +260us, r15 (float atomics) = +2us,
// r17 (ticket + threadfence) = +11us. Kernel boundaries are the cheap barrier.
//   k_sub2 (256x1024): tables in-block (block 0 exports sAT/sA/sLT, B-stats,
//                      Pi; blocks 0..84 export top label rows), path prior,
//                      down 5-7, up 7-5; exports TB4 + t_beta/ratio stash.
//   k_mid  (1x1024):   pure-import; top-down 0-3, top-up from TB4, full
//                      top-eps + top lh; exports EPSM + W_PART[256].
//   k_eps  (256x1024): import tables/stats; stash->LDS; subtree eps 4-7 + lh
//                      -> W_PART[bid].
//   k_final(1x256):    sum 257 partials -> out[0].
//
// Subtree r in [85,341): local m in [0,85), depth d, global g = 4^d*r + m;
// parent=(m-1)>>2, pos=(m-1)&3 hold locally. Class invariant: for level
// starts {1,5,21,85} and base stepping by 32, e=(m-1)&3 == grp&3.

#define NF (21845 * 32)

enum : int {
  W_TBETA = 0,              // [N][32] rows 85..21844
  W_RATIO = NF,             // [N][32] (beta_final/prior)
  W_TB4   = 2 * NF,         // [256][32] level-4 t_beta (index r-85)
  W_EPSM  = 2 * NF + 8192,  // [85][32] top eps rows
  W_PART  = W_EPSM + 2720,  // 257 lh partials
  W_TABA  = W_PART + 260,   // sAT  [e][j][i] sm            (4096)
  W_TABU  = W_TABA + 4096,  // sA   [e][i][j] sm            (4096)
  W_TABL  = W_TABU + 4096,  // sLT  [e][j][i] sm*log        (4096)
  W_BST   = W_TABL + 4096,  // bmx[32], binv[32], bls[32]   (96)
  W_PIV   = W_BST + 96,     // sPi[32], lPi[32]             (64)
  W_TOPS  = W_PIV + 64,     // top smB label rows [85][32]  (2720)
  W_TOPL  = W_TOPS + 2720,  // top logB label rows [85][32] (2720)
};

__device__ inline float hsum32(float v) {
#pragma unroll
  for (int m = 16; m >= 1; m >>= 1) v += __shfl_xor(v, m, 32);
  return v;
}
__device__ inline float hmax32(float v) {
#pragma unroll
  for (int m = 16; m >= 1; m >>= 1) v = fmaxf(v, __shfl_xor(v, m, 32));
  return v;
}
__device__ inline int gmap(int r, int m) {
  return (m == 0) ? r : (m < 5 ? 4 * r + m : (m < 21 ? 16 * r + m : 64 * r + m));
}

// reg-table matvec: out[lane] = sum_j T[j] * vec[j]; vec via b128 broadcast.
__device__ inline float mvreg(const float (&T)[32], const float* __restrict__ vec) {
  const float4* v4 = (const float4*)vec;
  float a0 = 0.f, a1 = 0.f, a2 = 0.f, a3 = 0.f;
#pragma unroll
  for (int j4 = 0; j4 < 8; j4++) {
    float4 v = v4[j4];
    a0 += T[4 * j4 + 0] * v.x; a1 += T[4 * j4 + 1] * v.y;
    a2 += T[4 * j4 + 2] * v.z; a3 += T[4 * j4 + 3] * v.w;
  }
  return (a0 + a1) + (a2 + a3);
}
__device__ inline void mvreg2(const float (&Tn)[32], const float (&Tl)[32],
                              const float* __restrict__ vec, float& an, float& aa) {
  const float4* v4 = (const float4*)vec;
  float n0 = 0.f, n1 = 0.f, n2 = 0.f, n3 = 0.f;
  float l0 = 0.f, l1 = 0.f, l2 = 0.f, l3 = 0.f;
#pragma unroll
  for (int j4 = 0; j4 < 8; j4++) {
    float4 v = v4[j4];
    n0 += Tn[4 * j4 + 0] * v.x; n1 += Tn[4 * j4 + 1] * v.y;
    n2 += Tn[4 * j4 + 2] * v.z; n3 += Tn[4 * j4 + 3] * v.w;
    l0 += Tl[4 * j4 + 0] * v.x; l1 += Tl[4 * j4 + 1] * v.y;
    l2 += Tl[4 * j4 + 2] * v.z; l3 += Tl[4 * j4 + 3] * v.w;
  }
  an = (n0 + n1) + (n2 + n3);
  aa = (l0 + l1) + (l2 + l3);
}

// ---------------- K1: per-subtree down 5-7 + up 7-5 + exports ---------------
__global__ __launch_bounds__(1024, 4) void k_sub2(const float* __restrict__ A,
                                                  const float* __restrict__ Bm,
                                                  const float* __restrict__ Pi,
                                                  const int* __restrict__ labels,
                                                  float* __restrict__ W) {
  __shared__ __align__(16) float sAT[4096], sA[4096];
  __shared__ __align__(16) float SH[10880];
  __shared__ float smx[128], sinv[128], sls[128];
  __shared__ float sBmx[32], sBinv[32], sBls[32];
  __shared__ __align__(16) float spath[32];
  __shared__ float sp3v[32];
  float* sp  = SH;          float* sb  = SH + 2720;
  float* stb = SH + 5440;   float* slb = SH + 8160;
  float* S   = SH;          // staging 4224 floats, dead after build

  const int tid = threadIdx.x, bid = blockIdx.x;
  const int grp = tid >> 5, lane = tid & 31;
  const int ecl = grp & 3, slot = grp >> 2;
  const int r = 85 + bid;

  {  // B row stats (+ export by block 0)
    float xs[8], mx = -1e30f;
#pragma unroll
    for (int k = 0; k < 8; k++) { xs[k] = Bm[grp * 256 + k * 32 + lane]; mx = fmaxf(mx, xs[k]); }
    mx = hmax32(mx);
    float s = 0.f;
#pragma unroll
    for (int k = 0; k < 8; k++) s += expf(xs[k] - mx);
    s = hsum32(s);
    if (lane == 0) {
      float ls = logf(s);
      sBmx[grp] = mx; sBinv[grp] = 1.f / s; sBls[grp] = ls;
      if (bid == 0) { W[W_BST + grp] = mx; W[W_BST + 32 + grp] = 1.f / s; W[W_BST + 64 + grp] = ls; }
    }
  }
  {  // stage raw A -> padded S
    float4 raw = ((const float4*)A)[tid];
    int i = tid >> 5, j = tid & 31;
    S[(j * 4 + 0) * 33 + i] = raw.x;
    S[(j * 4 + 1) * 33 + i] = raw.y;
    S[(j * 4 + 2) * 33 + i] = raw.z;
    S[(j * 4 + 3) * 33 + i] = raw.w;
  }
  __syncthreads();
  if (tid < 128) {  // column stats (c = j*4+e)
    int c = tid;
    float mx = -1e30f;
    for (int i = 0; i < 32; i++) mx = fmaxf(mx, S[c * 33 + i]);
    float s = 0.f;
    for (int i = 0; i < 32; i++) s += expf(S[c * 33 + i] - mx);
    smx[c] = mx; sinv[c] = 1.f / s; sls[c] = logf(s);
  }
  __syncthreads();
  {  // emit sAT [e][j][i]; block 0 also exports sAT + sLT (sm*log)
    int v = 4 * tid, e = v >> 10, j = (v >> 5) & 31, i0 = v & 31, c = j * 4 + e;
    float mx = smx[c], iv = sinv[c], ls = sls[c];
    float x0 = S[c * 33 + i0 + 0], x1 = S[c * 33 + i0 + 1];
    float x2 = S[c * 33 + i0 + 2], x3 = S[c * 33 + i0 + 3];
    float s0 = expf(x0 - mx) * iv, s1 = expf(x1 - mx) * iv;
    float s2 = expf(x2 - mx) * iv, s3 = expf(x3 - mx) * iv;
    float4 o; o.x = s0; o.y = s1; o.z = s2; o.w = s3;
    ((float4*)sAT)[tid] = o;
    if (bid == 0) {
      ((float4*)(W + W_TABA))[tid] = o;
      float4 ol;
      ol.x = s0 * ((x0 - mx) - ls); ol.y = s1 * ((x1 - mx) - ls);
      ol.z = s2 * ((x2 - mx) - ls); ol.w = s3 * ((x3 - mx) - ls);
      ((float4*)(W + W_TABL))[tid] = ol;
    }
  }
  {  // emit sA [e][i][j]; block 0 exports
    int v = 4 * tid, e = v >> 10, i = (v >> 5) & 31, j0 = v & 31;
    float4 o;
    { int c = (j0 + 0) * 4 + e; o.x = expf(S[c * 33 + i] - smx[c]) * sinv[c]; }
    { int c = (j0 + 1) * 4 + e; o.y = expf(S[c * 33 + i] - smx[c]) * sinv[c]; }
    { int c = (j0 + 2) * 4 + e; o.z = expf(S[c * 33 + i] - smx[c]) * sinv[c]; }
    { int c = (j0 + 3) * 4 + e; o.w = expf(S[c * 33 + i] - smx[c]) * sinv[c]; }
    ((float4*)sA)[tid] = o;
    if (bid == 0) ((float4*)(W + W_TABU))[tid] = o;
  }
  __syncthreads();  // S dead

  {  // smB label rows (static 3-slot)
    const int m0 = grp, m1 = grp + 32, m2 = grp + 64;
    float bmx = sBmx[lane], binv = sBinv[lane];
    float x0 = Bm[lane * 256 + labels[gmap(r, m0)]];
    float x1 = Bm[lane * 256 + labels[gmap(r, m1)]];
    slb[m0 * 32 + lane] = expf(x0 - bmx) * binv;
    slb[m1 * 32 + lane] = expf(x1 - bmx) * binv;
    if (m2 < 85) {
      float x2 = Bm[lane * 256 + labels[gmap(r, m2)]];
      slb[m2 * 32 + lane] = expf(x2 - bmx) * binv;
    }
  }
  // top label row export: block b (<85) exports top node b's row (sm + log)
  if (bid < 85 && tid < 32) {
    float x = Bm[tid * 256 + labels[bid]];
    W[W_TOPS + bid * 32 + tid] = expf(x - sBmx[tid]) * sBinv[tid];
    W[W_TOPL + bid * 32 + tid] = (x - sBmx[tid]) - sBls[tid];
  }
  {  // smPi -> spath (+ export by block 0)
    float x = Pi[lane];
    float mx = hmax32(x);
    float ex = expf(x - mx);
    float s = hsum32(ex);
    float pPi = ex / s;
    if (tid < 32) {
      spath[tid] = pPi;
      if (bid == 0) { W[W_PIV + tid] = pPi; W[W_PIV + 32 + tid] = (x - mx) - logf(s); }
    }
  }
  float D[32];
#pragma unroll
  for (int j = 0; j < 32; j++) D[j] = sAT[(grp & 3) * 1024 + j * 32 + lane];
  __syncthreads();

  const int a3n = (r - 1) >> 2, a2n = (a3n - 1) >> 2, a1n = (a2n - 1) >> 2;
  const int pe0 = (a1n - 1) & 3, pe1 = (a2n - 1) & 3, pe2 = (a3n - 1) & 3, pe3 = (r - 1) & 3;
  if (ecl == pe0 && slot == 0) spath[lane] = mvreg(D, spath);
  __syncthreads();
  if (ecl == pe1 && slot == 0) spath[lane] = mvreg(D, spath);
  __syncthreads();
  if (ecl == pe2 && slot == 0) { float a = mvreg(D, spath); spath[lane] = a; sp3v[lane] = a; }
  __syncthreads();
  if (ecl == pe3 && slot == 0) spath[lane] = mvreg(D, spath);
  __syncthreads();
  if (tid < 32) { sp[tid] = spath[tid]; sb[tid] = spath[tid] * slb[tid]; }
  __syncthreads();

  const int LOFF[5] = {0, 1, 5, 21, 85};
  for (int d = 1; d <= 3; d++) {
    int st = LOFF[d], cnt = LOFF[d + 1] - st;
    for (int base = 0; base < cnt; base += 32) {
      int ix = base + grp;
      if (ix < cnt) {
        int m = st + ix, pam = (m - 1) >> 2;
        float acc = mvreg(D, &sp[pam * 32]);
        sp[m * 32 + lane] = acc;
        float bv = acc * slb[m * 32 + lane];
        if (d == 3) bv /= hsum32(bv);
        sb[m * 32 + lane] = bv;
      }
    }
    __syncthreads();
  }
  float U[32];
#pragma unroll
  for (int i = 0; i < 32; i++) U[i] = sA[(grp & 3) * 1024 + i * 32 + lane];
  for (int d = 2; d >= 0; d--) {
    int pst = LOFF[d], pcnt = LOFF[d + 1] - pst;
    for (int base = 0; base < pcnt; base += 8) {
      int pidx = base + slot;
      if (pidx < pcnt) {
        int pn = pst + pidx;
        int mch = 4 * pn + 1 + ecl;
        stb[mch * 32 + lane] = mvreg(U, &sb[mch * 32]) / sp[pn * 32 + lane];
      }
    }
    __syncthreads();
    if (grp < pcnt) {
      int pn = pst + grp;
      float prod = stb[(4 * pn + 1) * 32 + lane] * stb[(4 * pn + 2) * 32 + lane]
                 * stb[(4 * pn + 3) * 32 + lane] * stb[(4 * pn + 4) * 32 + lane];
      float bn = sb[pn * 32 + lane] * prod;
      bn /= hsum32(bn);
      sb[pn * 32 + lane] = bn;
    }
    __syncthreads();
  }
  if (ecl == pe3 && slot == 0) {
    float acc = mvreg(U, &sb[0]);
    float tb = acc / sp3v[lane];
    stb[lane] = tb;
    W[W_TB4 + bid * 32 + lane] = tb;
  }
  __syncthreads();
  if (tid < 680) {
    int m = tid >> 3, q = tid & 7, g = gmap(r, m);
    *(float4*)&W[W_TBETA + g * 32 + q * 4] = *(float4*)&stb[m * 32 + q * 4];
    float4 bb = *(float4*)&sb[m * 32 + q * 4], pp = *(float4*)&sp[m * 32 + q * 4];
    float4 rr;
    rr.x = bb.x / pp.x; rr.y = bb.y / pp.y; rr.z = bb.z / pp.z; rr.w = bb.w / pp.w;
    *(float4*)&W[W_RATIO + g * 32 + q * 4] = rr;
  }
}

// ---------------- K2: top tree + full top-eps + top lh (pure import) --------
__global__ __launch_bounds__(1024, 4) void k_mid(float* __restrict__ W) {
  __shared__ __align__(16) float sAT[4096], sA[4096], sLT[4096];
  __shared__ __align__(16) float R[8192];    // TB4
  __shared__ __align__(16) float U[16320];
  __shared__ __align__(16) float sq[1024];
  __shared__ float sred[16];
  float* msp   = U;            float* msb   = U + 2720;
  float* mstb  = U + 5440;     float* mslbS = U + 8160;
  float* mseps = U + 10880;    float* mslbL = U + 13600;

  const int tid = threadIdx.x;
  const int grp = tid >> 5, lane = tid & 31;
  const int LOFF[5] = {0, 1, 5, 21, 85};

  // ---- issue ALL imports up front ----
  float4 tA = ((const float4*)(W + W_TABA))[tid];
  float4 tU = ((const float4*)(W + W_TABU))[tid];
  float4 tL = ((const float4*)(W + W_TABL))[tid];
  float4 r0 = ((const float4*)(W + W_TB4))[tid];
  float4 r1 = ((const float4*)(W + W_TB4))[tid + 1024];
  float4 tS, tLg;
  if (tid < 680) {
    tS  = ((const float4*)(W + W_TOPS))[tid];
    tLg = ((const float4*)(W + W_TOPL))[tid];
  }
  float pv = 0.f, lv = 0.f;
  if (tid < 32) { pv = W[W_PIV + tid]; lv = W[W_PIV + 32 + tid]; }

  ((float4*)sAT)[tid] = tA;
  ((float4*)sA)[tid]  = tU;
  ((float4*)sLT)[tid] = tL;
  ((float4*)R)[tid] = r0; ((float4*)R)[tid + 1024] = r1;
  if (tid < 680) { ((float4*)mslbS)[tid] = tS; ((float4*)mslbL)[tid] = tLg; }
  if (tid < 32) msp[tid] = pv;
  __syncthreads();

  float D[32], L[32];
#pragma unroll
  for (int j = 0; j < 32; j++) D[j] = sAT[(grp & 3) * 1024 + j * 32 + lane];
#pragma unroll
  for (int j = 0; j < 32; j++) L[j] = sLT[(grp & 3) * 1024 + j * 32 + lane];
  if (grp == 0) msb[lane] = msp[lane] * mslbS[lane];
  __syncthreads();

  // top-down levels 1..3
  for (int l = 1; l <= 3; l++) {
    int st = LOFF[l], cnt = LOFF[l + 1] - st;
    for (int base = 0; base < cnt; base += 32) {
      int ix = base + grp;
      if (ix < cnt) {
        int n = st + ix, pa = (n - 1) >> 2;
        float acc = mvreg(D, &msp[pa * 32]);
        msp[n * 32 + lane] = acc;
        msb[n * 32 + lane] = acc * mslbS[n * 32 + lane];
      }
    }
    __syncthreads();
  }
  // top-up: level-3 parents from TB4, then 2,1,0
  {
    for (int base = 0; base < 64; base += 32) {
      int ix = base + grp;
      if (ix < 64) {
        int pn = 21 + ix;
        float prod = 1.f;
#pragma unroll
        for (int c = 0; c < 4; c++) prod *= R[(4 * pn + 1 + c - 85) * 32 + lane];
        float bn = msb[pn * 32 + lane] * prod;
        bn /= hsum32(bn);
        msb[pn * 32 + lane] = bn;
      }
    }
    __syncthreads();
    const int PST[3] = {5, 1, 0}, PCNT[3] = {16, 4, 1};
    for (int s = 0; s < 3; s++) {
      int st = PST[s], cnt = PCNT[s];
      if (grp < cnt) {
        int pn = st + grp;
        float ppj = msp[pn * 32 + lane];
        float ac[4] = {0.f, 0.f, 0.f, 0.f};
#pragma unroll
        for (int j4 = 0; j4 < 8; j4++) {
#pragma unroll
          for (int c = 0; c < 4; c++) {
            float4 v = ((const float4*)&msb[(4 * pn + 1 + c) * 32])[j4];
            const float* t = &sA[c * 1024 + j4 * 128 + lane];
            ac[c] += t[0] * v.x + t[32] * v.y + t[64] * v.z + t[96] * v.w;
          }
        }
        float prod = 1.f;
#pragma unroll
        for (int c = 0; c < 4; c++) {
          float buv = ac[c] / ppj;
          mstb[(4 * pn + 1 + c) * 32 + lane] = buv;
          prod *= buv;
        }
        float bn = msb[pn * 32 + lane] * prod;
        bn /= hsum32(bn);
        msb[pn * 32 + lane] = bn;
      }
      __syncthreads();
    }
  }

  float lh = 0.f;
  if (grp == 0) {
    float v = msb[lane];
    mseps[lane] = v;
    lh += v * (lv + mslbL[lane]);  // Pi_lh + root B_lh
  }
  __syncthreads();
  const int EST[3] = {1, 5, 21}, ECNT[3] = {4, 16, 64};
  for (int s = 0; s < 3; s++) {
    int st = EST[s], cnt = ECNT[s];
    for (int base = 0; base < cnt; base += 32) {
      int ix = base + grp;
      if (ix < cnt) {
        int n = st + ix, pa = (n - 1) >> 2;
        float ratio = msb[n * 32 + lane] / msp[n * 32 + lane];
        float qv = mseps[pa * 32 + lane] / mstb[n * 32 + lane];
        sq[grp * 32 + lane] = qv;
        float an, aa;
        mvreg2(D, L, &sq[grp * 32], an, aa);
        float num = ratio * an;
        float den = hsum32(num);
        float epsi = num / den;
        mseps[n * 32 + lane] = epsi;
        lh += ratio * aa + epsi * mslbL[n * 32 + lane];
      }
    }
    __syncthreads();
  }
  if (tid < 680) {  // export eps rows 0..84
    int m = tid >> 3, q = tid & 7;
    *(float4*)&W[W_EPSM + m * 32 + q * 4] = *(float4*)&mseps[m * 32 + q * 4];
  }
#pragma unroll
  for (int mm = 32; mm >= 1; mm >>= 1) lh += __shfl_xor(lh, mm, 64);
  if ((tid & 63) == 0) sred[tid >> 6] = lh;
  __syncthreads();
  if (tid == 0) {
    float t = 0.f;
#pragma unroll
    for (int w = 0; w < 16; w++) t += sred[w];
    W[W_PART + 256] = t;
  }
}

// ---------------- K3: per-subtree eps 4-7 + lh (imports tables) -------------
__global__ __launch_bounds__(1024, 4) void k_eps(const float* __restrict__ Bm,
                                                 const int* __restrict__ labels,
                                                 float* __restrict__ W) {
  __shared__ __align__(16) float sAT[4096], sLT[4096];
  __shared__ __align__(16) float V[10880];
  __shared__ __align__(16) float sq[1024];
  __shared__ __align__(16) float sqr[32];
  __shared__ float spe[32];
  __shared__ float sbst[96];
  __shared__ float sred[16];
  float* stb  = V;            float* srt  = V + 2720;
  float* seps = V + 5440;     float* slbL = V + 8160;

  const int tid = threadIdx.x, bid = blockIdx.x;
  const int grp = tid >> 5, lane = tid & 31;
  const int ecl = grp & 3, slot = grp >> 2;
  const int r = 85 + bid;
  const int LOFF[5] = {0, 1, 5, 21, 85};

  // ---- issue ALL global loads up front ----
  float4 stT, stR;
  const int sm_ = tid >> 3, sq_ = tid & 7;
  if (tid < 680) {
    int g = gmap(r, sm_);
    stT = *(const float4*)&W[W_TBETA + g * 32 + sq_ * 4];
    stR = *(const float4*)&W[W_RATIO + g * 32 + sq_ * 4];
  }
  float4 tA = ((const float4*)(W + W_TABA))[tid];
  float4 tL = ((const float4*)(W + W_TABL))[tid];
  float pe = 0.f;
  if (tid < 32) pe = W[W_EPSM + ((r - 1) >> 2) * 32 + tid];
  float bv = 0.f;
  if (tid < 96) bv = W[W_BST + tid];
  const int m0 = grp, m1 = grp + 32, m2 = grp + 64;
  const bool h2 = (m2 < 85);
  int lb0 = labels[gmap(r, m0)];
  int lb1 = labels[gmap(r, m1)];
  int lb2 = h2 ? labels[gmap(r, m2)] : 0;
  float xs0 = Bm[lane * 256 + lb0];
  float xs1 = Bm[lane * 256 + lb1];
  float xs2 = h2 ? Bm[lane * 256 + lb2] : 0.f;

  ((float4*)sAT)[tid] = tA;
  ((float4*)sLT)[tid] = tL;
  if (tid < 32) spe[tid] = pe;
  if (tid < 96) sbst[tid] = bv;
  if (tid < 680) {
    *(float4*)&stb[sm_ * 32 + sq_ * 4] = stT;
    *(float4*)&srt[sm_ * 32 + sq_ * 4] = stR;
  }
  __syncthreads();

  {  // log-B label rows (bmx = sbst[lane], bls = sbst[64+lane])
    float bmx = sbst[lane], bls = sbst[64 + lane];
    slbL[m0 * 32 + lane] = (xs0 - bmx) - bls;
    slbL[m1 * 32 + lane] = (xs1 - bmx) - bls;
    if (h2) slbL[m2 * 32 + lane] = (xs2 - bmx) - bls;
  }
  float D[32], L[32];
#pragma unroll
  for (int j = 0; j < 32; j++) D[j] = sAT[(grp & 3) * 1024 + j * 32 + lane];
#pragma unroll
  for (int j = 0; j < 32; j++) L[j] = sLT[(grp & 3) * 1024 + j * 32 + lane];
  __syncthreads();

  float lh = 0.f;
  // eps at level-4 root r (class-matching group)
  if (ecl == ((r - 1) & 3) && slot == 0) {
    float ratio = srt[lane];
    sqr[lane] = spe[lane] / stb[lane];
    float an, aa;
    mvreg2(D, L, sqr, an, aa);
    float num = ratio * an;
    float den = hsum32(num);
    float epsi = num / den;
    seps[lane] = epsi;
    lh += ratio * aa + epsi * slbL[lane];
  }
  __syncthreads();
  // subtree eps levels 1..3 (global 5..7); e == grp&3
  for (int d = 1; d <= 3; d++) {
    int st = LOFF[d], cnt = LOFF[d + 1] - st;
    for (int base = 0; base < cnt; base += 32) {
      int ix = base + grp;
      if (ix < cnt) {
        int m = st + ix, pa = (m - 1) >> 2;
        float ratio = srt[m * 32 + lane];
        sq[grp * 32 + lane] = seps[pa * 32 + lane] / stb[m * 32 + lane];
        float an, aa;
        mvreg2(D, L, &sq[grp * 32], an, aa);
        float num = ratio * an;
        float den = hsum32(num);
        float epsi = num / den;
        seps[m * 32 + lane] = epsi;
        lh += ratio * aa + epsi * slbL[m * 32 + lane];
      }
    }
    __syncthreads();
  }

#pragma unroll
  for (int mm = 32; mm >= 1; mm >>= 1) lh += __shfl_xor(lh, mm, 64);
  if ((tid & 63) == 0) sred[tid >> 6] = lh;
  __syncthreads();
  if (tid == 0) {
    float t = 0.f;
#pragma unroll
    for (int w = 0; w < 16; w++) t += sred[w];
    W[W_PART + bid] = t;
  }
}

// ---------------- K4: final reduce (no atomics) ------------------------------
__global__ void k_final(const float* __restrict__ W, float* __restrict__ out) {
  __shared__ float sh[256];
  int tid = threadIdx.x;
  float a = 0.f;
  for (int k = tid; k < 257; k += 256) a += W[W_PART + k];
  sh[tid] = a; __syncthreads();
  for (int off = 128; off >= 1; off >>= 1) {
    if (tid < off) sh[tid] += sh[tid + off];
    __syncthreads();
  }
  if (tid == 0) out[0] = sh[0];
}

extern "C" void kernel_launch(void* const* d_in, const int* in_sizes, int n_in,
                              void* d_out, int out_size, void* d_ws, size_t ws_size,
                              hipStream_t stream) {
  const float* A  = (const float*)d_in[0];
  const float* Bm = (const float*)d_in[1];
  const float* Pi = (const float*)d_in[2];
  const int* labels = (const int*)d_in[5];
  float* W = (float*)d_ws;
  float* out = (float*)d_out;

  k_sub2<<<256, 1024, 0, stream>>>(A, Bm, Pi, labels, W);
  k_mid<<<1, 1024, 0, stream>>>(W);
  k_eps<<<256, 1024, 0, stream>>>(Bm, labels, W);
  k_final<<<1, 256, 0, stream>>>(W, out);
}